// Round 8
// baseline (483.986 us; speedup 1.0000x reference)
//
#include <hip/hip_runtime.h>
#include <math.h>

#define H 512
#define GV 640
#define E_DIM 256
#define BM 64
#define KSTEP 32
#define NKT (H / KSTEP)   // 16

typedef _Float16 half8 __attribute__((ext_vector_type(8)));
typedef float f32x4 __attribute__((ext_vector_type(4)));

// ws layout
#define WS_WH   4096
#define WS_WL   (WS_WH + 655360)
#define WS_CVAL (WS_WL + 655360)
#define WS_CIDX (WS_CVAL + 65536 * 10 * 4)
#define WS_NEED_FULL (WS_CIDX + 65536 * 10 * 4)
#define WS_NEED_MID  (4096 + 2 * 655360)

// ---------------- prep: W (640x512 f32) -> fp16 hi/lo images, fragment-order ----------------
// Granule t (16 B = half8): kt = t/2560, g = (t%2560)/640, col = t%640.
// Holds W[col][kt*32 + g*8 .. +8] scaled by 1024; lo = UNSCALED residual.
__global__ void prep_w(const float* __restrict__ W, _Float16* __restrict__ wh,
                       _Float16* __restrict__ wl)
{
    int t = blockIdx.x * 256 + threadIdx.x;      // 0..40959
    int kt = t / 2560;
    int rem = t % 2560;
    int g = rem / 640;
    int col = rem - g * 640;
    int k = kt * KSTEP + g * 8;
    const float* src = W + (size_t)col * H + k;
    float4 v0 = *(const float4*)src;
    float4 v1 = *(const float4*)(src + 4);
    float vv[8] = {v0.x, v0.y, v0.z, v0.w, v1.x, v1.y, v1.z, v1.w};
    half8 hv, lv;
    #pragma unroll
    for (int i = 0; i < 8; ++i) {
        float ws_ = vv[i] * 1024.0f;
        _Float16 h = (_Float16)ws_;
        hv[i] = h;
        lv[i] = (_Float16)(ws_ - (float)h);
    }
    ((half8*)wh)[t] = hv;
    ((half8*)wl)[t] = lv;
}

// ---------------- main GEMM kernel: 32x32 wave tiles, barrier-free K-loop ----------------
// Grid 10240 (XCD-chunk-swizzled): logical lb -> rowslice = lb/10, colblk = lb%10.
// Block 256 thr = 4 waves (2x2); wave (wr,wc) owns rows wr*32..+32, cols wc*32..+32
// of the block's 64x64 tile. acc = 2x2 f32x4 = 16 regs -> total ~60 -> 8 waves/SIMD.
// Emits per-(row, colblk) argmax candidates to ws; no cross-group work here.
__global__ __launch_bounds__(256) void gemm32(
    const float* __restrict__ hid,     // (B,512)
    const float* __restrict__ noise,   // (B,640)
    const float* __restrict__ bias,    // (640)
    const _Float16* __restrict__ wh,
    const _Float16* __restrict__ wl,
    float* __restrict__ cval,          // (B,10)
    int* __restrict__ cidx)            // (B,10)
{
    __shared__ float vlds[BM][2];
    __shared__ int   ilds[BM][2];

    // XCD-chunk swizzle: 10240 % 8 == 0 -> bijective; consecutive logical blocks
    // (same row-slice) land on the same XCD for hid L2 reuse.
    const int lb = (blockIdx.x & 7) * 1280 + (blockIdx.x >> 3);
    const int rowslice = lb / 10;
    const int colblk = lb - rowslice * 10;
    const int brow = rowslice * BM;
    const int colbase = colblk * 64;

    const int tid = threadIdx.x;
    const int wid = tid >> 6;
    const int wr = wid >> 1, wc = wid & 1;
    const int l = tid & 63;
    const int q = l & 15, g = l >> 4;

    f32x4 acc[2][2];
    #pragma unroll
    for (int mt = 0; mt < 2; ++mt)
        #pragma unroll
        for (int nt = 0; nt < 2; ++nt)
            acc[mt][nt] = (f32x4){0.f, 0.f, 0.f, 0.f};

    const half8* whv = (const half8*)wh;
    const half8* wlv = (const half8*)wl;

    for (int kt = 0; kt < NKT; ++kt) {
        // A fragments: direct global load (16 rows x 128B contiguous) + in-reg split
        half8 Ah[2], Al[2];
        #pragma unroll
        for (int mt = 0; mt < 2; ++mt) {
            const float* aptr = hid + (size_t)(brow + wr * 32 + mt * 16 + q) * H
                                + kt * KSTEP + g * 8;
            float4 a0 = *(const float4*)aptr;
            float4 a1 = *(const float4*)(aptr + 4);
            float vv[8] = {a0.x, a0.y, a0.z, a0.w, a1.x, a1.y, a1.z, a1.w};
            half8 hv, lv;
            #pragma unroll
            for (int i = 0; i < 8; ++i) {
                float xs = vv[i] * 64.0f;
                _Float16 h = (_Float16)xs;
                hv[i] = h;
                lv[i] = (_Float16)(xs - (float)h);
            }
            Ah[mt] = hv;
            Al[mt] = lv;
        }

        const int gbase = (kt * 4 + g) * 640 + colbase + wc * 32 + q;
        #pragma unroll
        for (int nt = 0; nt < 2; ++nt) {
            half8 Bh = whv[gbase + nt * 16];
            half8 Bl = wlv[gbase + nt * 16];
            #pragma unroll
            for (int mt = 0; mt < 2; ++mt) {
                acc[mt][nt] = __builtin_amdgcn_mfma_f32_16x16x32_f16(Ah[mt], Bh, acc[mt][nt], 0, 0, 0);
                acc[mt][nt] = __builtin_amdgcn_mfma_f32_16x16x32_f16(Ah[mt], Bl, acc[mt][nt], 0, 0, 0);
                acc[mt][nt] = __builtin_amdgcn_mfma_f32_16x16x32_f16(Al[mt], Bh, acc[mt][nt], 0, 0, 0);
            }
        }
    }

    // ---- epilogue: z = logits + bias + gumbel; argmax over this wave's 32 cols ----
    const float C1 = 1.52587890625e-05f;        // 2^-16
    float bcol[2];
    #pragma unroll
    for (int nt = 0; nt < 2; ++nt) bcol[nt] = bias[colbase + wc * 32 + nt * 16 + q];

    #pragma unroll
    for (int mt = 0; mt < 2; ++mt) {
        #pragma unroll
        for (int reg = 0; reg < 4; ++reg) {
            const int rloc = wr * 32 + mt * 16 + g * 4 + reg;   // row within block
            float bv = -INFINITY;
            int bn = 0;
            #pragma unroll
            for (int nt = 0; nt < 2; ++nt) {
                int col = colbase + wc * 32 + nt * 16 + q;
                float u = noise[(size_t)(brow + rloc) * GV + col];
                float gum = -logf(-logf(u + 1e-10f) + 1e-10f);
                float z = acc[mt][nt][reg] * C1 + bcol[nt] + gum;
                if (z > bv) { bv = z; bn = col; }               // ascending: first-wins
            }
            #pragma unroll
            for (int m = 1; m < 16; m <<= 1) {                  // 16-lane argmax reduce
                float ov = __shfl_xor(bv, m, 64);
                int on = __shfl_xor(bn, m, 64);
                if (ov > bv || (ov == bv && on < bn)) { bv = ov; bn = on; }
            }
            if (q == 0) { vlds[rloc][wc] = bv; ilds[rloc][wc] = bn; }
        }
    }
    __syncthreads();

    // ---- combine the 2 col-waves; emit candidate for (row, colblk) ----
    if (tid < BM) {
        float bv = vlds[tid][0];
        int bn = ilds[tid][0];
        float v1 = vlds[tid][1];
        int n1 = ilds[tid][1];
        if (v1 > bv) { bv = v1; bn = n1; }                      // wc0 cols < wc1 cols
        cval[(size_t)(brow + tid) * 10 + colblk] = bv;
        cidx[(size_t)(brow + tid) * 10 + colblk] = bn;
    }
}

// ---------------- reduce: final argmax per (row,group), histogram, gather ----------------
// 4 tasks per 256-thr block; 64 lanes per task. All lanes redundantly compute the
// 5-candidate argmax (L2-hot), lane 0 updates the histogram, all gather 1KB coalesced.
__global__ __launch_bounds__(256) void reduce_gather(
    const float* __restrict__ cval, const int* __restrict__ cidx,
    const float* __restrict__ emb, float* __restrict__ out, int* __restrict__ cnt)
{
    const int tid = threadIdx.x;
    const int task = blockIdx.x * 4 + (tid >> 6);
    const int lane = tid & 63;
    const int row = task >> 1, grp = task & 1;

    float bv = -INFINITY;
    int bn = 0;
    #pragma unroll
    for (int cb = 0; cb < 5; ++cb) {
        float v = cval[(size_t)row * 10 + grp * 5 + cb];
        int n = cidx[(size_t)row * 10 + grp * 5 + cb];
        if (v > bv) { bv = v; bn = n; }                         // ascending colblk
    }
    if (lane == 0) atomicAdd(&cnt[bn], 1);
    const float4* src = (const float4*)(emb + (size_t)bn * E_DIM);
    float4* dst = (float4*)(out + (size_t)row * 512 + grp * 256);
    dst[lane] = src[lane];
}

__global__ void ppl_kernel(const int* __restrict__ cnt, float* __restrict__ outp)
{
    const int lane = threadIdx.x;
    float total = 0.f;
    #pragma unroll
    for (int gg = 0; gg < 2; ++gg) {
        float s = 0.f;
        for (int v = lane; v < 320; v += 64) {
            float m = (float)cnt[gg * 320 + v] * (1.0f / 65536.0f);
            s += m * logf(m + 1e-7f);
        }
        #pragma unroll
        for (int msk = 1; msk <= 32; msk <<= 1) s += __shfl_xor(s, msk, 64);
        total += expf(-s);
    }
    if (lane == 0) *outp = total;
}

// ---------------- mid fallback: round-4 kernel (needs only wh/wl in ws) ----------------
__global__ __launch_bounds__(640) void gemm_argmax_mid(
    const float* __restrict__ hid, const float* __restrict__ noise,
    const float* __restrict__ emb, const float* __restrict__ bias,
    const _Float16* __restrict__ wh, const _Float16* __restrict__ wl,
    float* __restrict__ out, int* __restrict__ cnt)
{
    __shared__ __align__(16) _Float16 Xh[BM][KSTEP];
    __shared__ __align__(16) _Float16 Xl[BM][KSTEP];
    __shared__ int sel_n[BM][2];
    float* red_val = (float*)&Xh[0][0];
    int*   red_idx = (int*)&Xl[0][0];

    const int tid = threadIdx.x;
    const int w = tid >> 6;
    const int l = tid & 63;
    const int q = l & 15, g = l >> 4;
    const int sig = (q >> 1) & 3;
    const int sl = (g ^ sig) * 8;
    const int brow = blockIdx.x * BM;

    f32x4 acc[4][4];
    #pragma unroll
    for (int mt = 0; mt < 4; ++mt)
        #pragma unroll
        for (int nt = 0; nt < 4; ++nt) acc[mt][nt] = (f32x4){0.f, 0.f, 0.f, 0.f};

    const half8* whv = (const half8*)wh;
    const half8* wlv = (const half8*)wl;

    for (int kt = 0; kt < NKT; ++kt) {
        __syncthreads();
        if (tid < 256) {
            int r = tid & 63, c = tid >> 6;
            const float* src = hid + (size_t)(brow + r) * H + kt * KSTEP + c * 8;
            float4 v0 = *(const float4*)src;
            float4 v1 = *(const float4*)(src + 4);
            float vv[8] = {v0.x, v0.y, v0.z, v0.w, v1.x, v1.y, v1.z, v1.w};
            half8 hv, lv;
            #pragma unroll
            for (int i = 0; i < 8; ++i) {
                float xs = vv[i] * 64.0f;
                _Float16 h = (_Float16)xs;
                hv[i] = h;
                lv[i] = (_Float16)(xs - (float)h);
            }
            int slot = c ^ ((r >> 1) & 3);
            *(half8*)&Xh[r][slot * 8] = hv;
            *(half8*)&Xl[r][slot * 8] = lv;
        }
        __syncthreads();
        half8 Ah[4], Al[4];
        #pragma unroll
        for (int mt = 0; mt < 4; ++mt) {
            int row = mt * 16 + q;
            Ah[mt] = *(const half8*)&Xh[row][sl];
            Al[mt] = *(const half8*)&Xl[row][sl];
        }
        const int gbase = (kt * 4 + g) * 640 + w * 64 + q;
        #pragma unroll
        for (int nt = 0; nt < 4; ++nt) {
            half8 Bh = whv[gbase + nt * 16];
            half8 Bl = wlv[gbase + nt * 16];
            #pragma unroll
            for (int mt = 0; mt < 4; ++mt) {
                acc[mt][nt] = __builtin_amdgcn_mfma_f32_16x16x32_f16(Ah[mt], Bh, acc[mt][nt], 0, 0, 0);
                acc[mt][nt] = __builtin_amdgcn_mfma_f32_16x16x32_f16(Ah[mt], Bl, acc[mt][nt], 0, 0, 0);
                acc[mt][nt] = __builtin_amdgcn_mfma_f32_16x16x32_f16(Al[mt], Bh, acc[mt][nt], 0, 0, 0);
            }
        }
    }
    __syncthreads();

    const float C1 = 1.52587890625e-05f;
    float bcol[4];
    #pragma unroll
    for (int nt = 0; nt < 4; ++nt) bcol[nt] = bias[w * 64 + nt * 16 + q];
    #pragma unroll
    for (int mt = 0; mt < 4; ++mt) {
        #pragma unroll
        for (int reg = 0; reg < 4; ++reg) {
            int r = mt * 16 + 4 * g + reg;
            float bv = -INFINITY;
            int bn = 0;
            #pragma unroll
            for (int nt = 0; nt < 4; ++nt) {
                int col = w * 64 + nt * 16 + q;
                float u = noise[(size_t)(brow + r) * GV + col];
                float gum = -logf(-logf(u + 1e-10f) + 1e-10f);
                float z = acc[mt][nt][reg] * C1 + bcol[nt] + gum;
                if (z > bv) { bv = z; bn = col; }
            }
            #pragma unroll
            for (int m = 1; m < 16; m <<= 1) {
                float ov = __shfl_xor(bv, m, 64);
                int on = __shfl_xor(bn, m, 64);
                if (ov > bv || (ov == bv && on < bn)) { bv = ov; bn = on; }
            }
            if (q == 0) { red_val[r * 10 + w] = bv; red_idx[r * 10 + w] = bn; }
        }
    }
    __syncthreads();
    if (tid < 128) {
        int r = tid >> 1, grp = tid & 1;
        float bv = -INFINITY;
        int bn = 0;
        #pragma unroll
        for (int ww = 0; ww < 5; ++ww) {
            int wi = grp * 5 + ww;
            float v = red_val[r * 10 + wi];
            int n = red_idx[r * 10 + wi];
            if (v > bv) { bv = v; bn = n; }
        }
        atomicAdd(&cnt[bn], 1);
        sel_n[r][grp] = bn;
    }
    __syncthreads();
    if (tid < 512) {
        int rg = tid >> 2, sub = tid & 3;
        int r = rg >> 1, grp = rg & 1;
        int n = sel_n[r][grp];
        const float4* src = (const float4*)(emb + (size_t)n * E_DIM);
        float4* dst = (float4*)(out + (size_t)(brow + r) * 512 + grp * 256);
        #pragma unroll
        for (int j = 0; j < 16; ++j) dst[sub + j * 4] = src[sub + j * 4];
    }
}

// ---------------- last-resort fp32 fallback (round-1) ----------------
__global__ __launch_bounds__(512) void fused_gemm_argmax(
    const float* __restrict__ hid, const float* __restrict__ noise,
    const float* __restrict__ emb, const float* __restrict__ W,
    const float* __restrict__ bias, float* __restrict__ out, int* __restrict__ cnt)
{
    __shared__ float A_lds[16][64];
    __shared__ float B_lds[16][GV + 4];
    const int tid = threadIdx.x;
    const int tx = tid & 63, ty = tid >> 6;
    const int brow = blockIdx.x * 64;
    const int nbase = tx * 10;
    float acc[8][10];
    #pragma unroll
    for (int i = 0; i < 8; ++i)
        #pragma unroll
        for (int j = 0; j < 10; ++j) acc[i][j] = 0.f;
    for (int t = 0; t < H; t += 16) {
        if (t) __syncthreads();
        if (tid < 256) {
            int m = tid & 63, kq = tid >> 6;
            float4 v = *(const float4*)(hid + (size_t)(brow + m) * H + t + kq * 4);
            A_lds[kq * 4 + 0][m] = v.x; A_lds[kq * 4 + 1][m] = v.y;
            A_lds[kq * 4 + 2][m] = v.z; A_lds[kq * 4 + 3][m] = v.w;
        }
        #pragma unroll
        for (int s = 0; s < 5; ++s) {
            int c = tid + s * 512;
            int n = c % 640, kq = c / 640;
            float4 v = *(const float4*)(W + (size_t)n * H + t + kq * 4);
            B_lds[kq * 4 + 0][n] = v.x; B_lds[kq * 4 + 1][n] = v.y;
            B_lds[kq * 4 + 2][n] = v.z; B_lds[kq * 4 + 3][n] = v.w;
        }
        __syncthreads();
        #pragma unroll 4
        for (int kk = 0; kk < 16; ++kk) {
            float a[8], bb[10];
            #pragma unroll
            for (int i = 0; i < 8; ++i) a[i] = A_lds[kk][ty * 8 + i];
            #pragma unroll
            for (int j = 0; j < 10; ++j) bb[j] = B_lds[kk][nbase + j];
            #pragma unroll
            for (int i = 0; i < 8; ++i)
                #pragma unroll
                for (int j = 0; j < 10; ++j) acc[i][j] = fmaf(a[i], bb[j], acc[i][j]);
        }
    }
    float bs[10];
    #pragma unroll
    for (int j = 0; j < 10; ++j) bs[j] = bias[nbase + j];
    const int gg = tx >> 5, ll = tx & 31;
    #pragma unroll
    for (int i = 0; i < 8; ++i) {
        const int b = brow + ty * 8 + i;
        float best = -INFINITY; int bestn = nbase;
        #pragma unroll
        for (int j = 0; j < 10; ++j) {
            float u = noise[(size_t)b * GV + nbase + j];
            float gmb = -logf(-logf(u + 1e-10f) + 1e-10f);
            float z = acc[i][j] + bs[j] + gmb;
            if (z > best) { best = z; bestn = nbase + j; }
        }
        #pragma unroll
        for (int msk = 1; msk <= 16; msk <<= 1) {
            float oz = __shfl_xor(best, msk, 64);
            int on = __shfl_xor(bestn, msk, 64);
            if (oz > best || (oz == best && on < bestn)) { best = oz; bestn = on; }
        }
        if (ll == 0) atomicAdd(&cnt[bestn], 1);
        const float4* src = (const float4*)(emb + (size_t)bestn * E_DIM);
        float4* dst = (float4*)(out + (size_t)b * 512 + gg * 256);
        dst[ll] = src[ll];
        dst[ll + 32] = src[ll + 32];
    }
}

extern "C" void kernel_launch(void* const* d_in, const int* in_sizes, int n_in,
                              void* d_out, int out_size, void* d_ws, size_t ws_size,
                              hipStream_t stream)
{
    const float* hid   = (const float*)d_in[0];
    const float* noise = (const float*)d_in[1];
    const float* emb   = (const float*)d_in[2];
    const float* W     = (const float*)d_in[3];
    const float* bias  = (const float*)d_in[4];
    float* out = (float*)d_out;
    int* cnt = (int*)d_ws;
    const int B = in_sizes[0] / H;

    hipMemsetAsync(cnt, 0, GV * sizeof(int), stream);
    if (ws_size >= (size_t)WS_NEED_FULL) {
        _Float16* wh = (_Float16*)((char*)d_ws + WS_WH);
        _Float16* wl = (_Float16*)((char*)d_ws + WS_WL);
        float* cv = (float*)((char*)d_ws + WS_CVAL);
        int* ci = (int*)((char*)d_ws + WS_CIDX);
        prep_w<<<160, 256, 0, stream>>>(W, wh, wl);
        gemm32<<<(B / BM) * 10, 256, 0, stream>>>(hid, noise, bias, wh, wl, cv, ci);
        reduce_gather<<<(B * 2) / 4, 256, 0, stream>>>(cv, ci, emb, out, cnt);
    } else if (ws_size >= (size_t)WS_NEED_MID) {
        _Float16* wh = (_Float16*)((char*)d_ws + WS_WH);
        _Float16* wl = (_Float16*)((char*)d_ws + WS_WL);
        prep_w<<<160, 256, 0, stream>>>(W, wh, wl);
        gemm_argmax_mid<<<B / BM, 640, 0, stream>>>(hid, noise, emb, bias, wh, wl, out, cnt);
    } else {
        fused_gemm_argmax<<<B / BM, 512, 0, stream>>>(hid, noise, emb, W, bias, out, cnt);
    }
    ppl_kernel<<<1, 64, 0, stream>>>(cnt, out + (size_t)B * 512);
}

// Round 9
// 425.808 us; speedup vs baseline: 1.1366x; 1.1366x over previous
//
#include <hip/hip_runtime.h>
#include <math.h>

#define H 512
#define GV 640
#define E_DIM 256
#define BM 64
#define KSTEP 32
#define NKT (H / KSTEP)   // 16

typedef _Float16 half8 __attribute__((ext_vector_type(8)));
typedef float f32x4 __attribute__((ext_vector_type(4)));

// ---- ws layout (interleaved hi/lo images: granule = 32 B = {half8 hi, half8 lo}) ----
#define WS_WI   4096                                   // W image: 40960 granules
#define WS_XI   (WS_WI + 40960 * 32)                   // X image: (B*64) granules
#define WS_CVAL(B) (WS_XI + (size_t)(B) * 64 * 32)
#define WS_CIDX(B) (WS_CVAL(B) + (size_t)(B) * 10 * 4)
#define WS_NEED_FULL(B) (WS_CIDX(B) + (size_t)(B) * 10 * 4)
#define WS_NEED_MID  (WS_WI + 40960 * 32)

// ---------------- prep W: (640x512 f32) -> interleaved fp16 hi/lo, fragment-order ----------------
// Granule t: kt=t/2560, g=(t%2560)/640, col=t%640. Holds W[col][kt*32+g*8..+8],
// hi scaled by 1024, lo = unscaled residual (same 2^16 product scale -> one acc).
__global__ void prep_w(const float* __restrict__ W, _Float16* __restrict__ wi)
{
    int t = blockIdx.x * 256 + threadIdx.x;      // 0..40959
    int kt = t / 2560;
    int rem = t % 2560;
    int g = rem / 640;
    int col = rem - g * 640;
    int k = kt * KSTEP + g * 8;
    const float* src = W + (size_t)col * H + k;
    float4 v0 = *(const float4*)src;
    float4 v1 = *(const float4*)(src + 4);
    float vv[8] = {v0.x, v0.y, v0.z, v0.w, v1.x, v1.y, v1.z, v1.w};
    half8 hv, lv;
    #pragma unroll
    for (int i = 0; i < 8; ++i) {
        float ws_ = vv[i] * 1024.0f;
        _Float16 h = (_Float16)ws_;
        hv[i] = h;
        lv[i] = (_Float16)(ws_ - (float)h);
    }
    ((half8*)wi)[2 * t]     = hv;
    ((half8*)wi)[2 * t + 1] = lv;
}

// ---------------- prep X: (B x 512 f32) -> interleaved fp16 hi/lo, row-major granules ----------
// Granule t: row = t>>6, c = t&63 (k = c*8). Reads 32 B contiguous, writes 32 B contiguous.
__global__ void prep_x(const float* __restrict__ hid, _Float16* __restrict__ xi)
{
    int t = blockIdx.x * 256 + threadIdx.x;
    int row = t >> 6, c = t & 63;
    const float* src = hid + (size_t)row * H + c * 8;
    float4 v0 = *(const float4*)src;
    float4 v1 = *(const float4*)(src + 4);
    float vv[8] = {v0.x, v0.y, v0.z, v0.w, v1.x, v1.y, v1.z, v1.w};
    half8 hv, lv;
    #pragma unroll
    for (int i = 0; i < 8; ++i) {
        float xs = vv[i] * 64.0f;
        _Float16 h = (_Float16)xs;
        hv[i] = h;
        lv[i] = (_Float16)(xs - (float)h);
    }
    ((half8*)xi)[2 * t]     = hv;
    ((half8*)xi)[2 * t + 1] = lv;
}

// ---------------- main GEMM: barrier-free, zero LDS, pure pre-converted streams -------------
// Grid (B/64)*5, XCD-chunked. Block 256 thr = 4 waves (wr,wc in 2x2): 64 rows x 128 cols.
// Wave = 32 rows x 64 cols: acc[2][4] (32 regs), 12 loads + 24 MFMA per kt, no sync at all.
// Emits per-(row, 64-col-block) argmax candidates; cross-strip reduce done by reduce_gather.
__global__ __launch_bounds__(256, 4) void gemm32i(
    const float* __restrict__ noise,   // (B,640)
    const float* __restrict__ bias,    // (640)
    const _Float16* __restrict__ wi,   // interleaved W image
    const _Float16* __restrict__ xi,   // interleaved X image
    float* __restrict__ cval,          // (B,10)
    int* __restrict__ cidx)            // (B,10)
{
    int bid = blockIdx.x, nb = gridDim.x;
    const int lb = ((nb & 7) == 0) ? ((bid & 7) * (nb >> 3) + (bid >> 3)) : bid;
    const int rowslice = lb / 5;
    const int cb2 = lb - rowslice * 5;           // 128-col block 0..4
    const int brow = rowslice * BM;

    const int tid = threadIdx.x;
    const int wid = tid >> 6;
    const int wr = wid >> 1, wc = wid & 1;
    const int l = tid & 63;
    const int q = l & 15, g = l >> 4;
    const int colw = cb2 * 128 + wc * 64;        // wave's col base

    f32x4 acc[2][4];
    #pragma unroll
    for (int mt = 0; mt < 2; ++mt)
        #pragma unroll
        for (int nt = 0; nt < 4; ++nt)
            acc[mt][nt] = (f32x4){0.f, 0.f, 0.f, 0.f};

    const half8* xv = (const half8*)xi;
    const half8* wv = (const half8*)wi;

    #pragma unroll 4
    for (int kt = 0; kt < NKT; ++kt) {
        half8 Ah[2], Al[2];
        #pragma unroll
        for (int mt = 0; mt < 2; ++mt) {
            size_t ga = (size_t)(brow + wr * 32 + mt * 16 + q) * 64 + kt * 4 + g;
            Ah[mt] = xv[2 * ga];
            Al[mt] = xv[2 * ga + 1];
        }
        const int gb0 = (kt * 4 + g) * 640 + colw + q;
        #pragma unroll
        for (int nt = 0; nt < 4; ++nt) {
            half8 Bh = wv[2 * (gb0 + nt * 16)];
            half8 Bl = wv[2 * (gb0 + nt * 16) + 1];
            #pragma unroll
            for (int mt = 0; mt < 2; ++mt) {
                acc[mt][nt] = __builtin_amdgcn_mfma_f32_16x16x32_f16(Ah[mt], Bh, acc[mt][nt], 0, 0, 0);
                acc[mt][nt] = __builtin_amdgcn_mfma_f32_16x16x32_f16(Ah[mt], Bl, acc[mt][nt], 0, 0, 0);
                acc[mt][nt] = __builtin_amdgcn_mfma_f32_16x16x32_f16(Al[mt], Bh, acc[mt][nt], 0, 0, 0);
            }
        }
    }

    // ---- epilogue: z = logits + bias + gumbel; per-row argmax over this wave's 64 cols ----
    const float C1 = 1.52587890625e-05f;        // 2^-16 (64*1024 product scale)
    float bcol[4];
    #pragma unroll
    for (int nt = 0; nt < 4; ++nt) bcol[nt] = bias[colw + nt * 16 + q];

    const int cb10 = cb2 * 2 + wc;               // 64-col candidate slot 0..9
    #pragma unroll
    for (int mt = 0; mt < 2; ++mt) {
        #pragma unroll
        for (int reg = 0; reg < 4; ++reg) {
            const int rloc = wr * 32 + mt * 16 + g * 4 + reg;
            float bv = -INFINITY;
            int bn = 0;
            #pragma unroll
            for (int nt = 0; nt < 4; ++nt) {
                int col = colw + nt * 16 + q;
                float u = noise[(size_t)(brow + rloc) * GV + col];
                float gum = -logf(-logf(u + 1e-10f) + 1e-10f);
                float z = acc[mt][nt][reg] * C1 + bcol[nt] + gum;
                if (z > bv) { bv = z; bn = col; }            // ascending: first-wins
            }
            #pragma unroll
            for (int m = 1; m < 16; m <<= 1) {               // 16-lane argmax reduce
                float ov = __shfl_xor(bv, m, 64);
                int on = __shfl_xor(bn, m, 64);
                if (ov > bv || (ov == bv && on < bn)) { bv = ov; bn = on; }
            }
            if (q == 0) {
                cval[(size_t)(brow + rloc) * 10 + cb10] = bv;
                cidx[(size_t)(brow + rloc) * 10 + cb10] = bn;
            }
        }
    }
}

// ---------------- reduce: final argmax per (row,group), histogram, gather ----------------
__global__ __launch_bounds__(256) void reduce_gather(
    const float* __restrict__ cval, const int* __restrict__ cidx,
    const float* __restrict__ emb, float* __restrict__ out, int* __restrict__ cnt)
{
    const int tid = threadIdx.x;
    const int task = blockIdx.x * 4 + (tid >> 6);
    const int lane = tid & 63;
    const int row = task >> 1, grp = task & 1;

    float bv = -INFINITY;
    int bn = 0;
    #pragma unroll
    for (int cb = 0; cb < 5; ++cb) {
        float v = cval[(size_t)row * 10 + grp * 5 + cb];
        int n = cidx[(size_t)row * 10 + grp * 5 + cb];
        if (v > bv) { bv = v; bn = n; }                      // ascending colblk
    }
    if (lane == 0) atomicAdd(&cnt[bn], 1);
    const float4* src = (const float4*)(emb + (size_t)bn * E_DIM);
    float4* dst = (float4*)(out + (size_t)row * 512 + grp * 256);
    dst[lane] = src[lane];
}

__global__ void ppl_kernel(const int* __restrict__ cnt, float* __restrict__ outp)
{
    const int lane = threadIdx.x;
    float total = 0.f;
    #pragma unroll
    for (int gg = 0; gg < 2; ++gg) {
        float s = 0.f;
        for (int v = lane; v < 320; v += 64) {
            float m = (float)cnt[gg * 320 + v] * (1.0f / 65536.0f);
            s += m * logf(m + 1e-7f);
        }
        #pragma unroll
        for (int msk = 1; msk <= 32; msk <<= 1) s += __shfl_xor(s, msk, 64);
        total += expf(-s);
    }
    if (lane == 0) *outp = total;
}

// ---------------- mid fallback: round-4 kernel (interleaved W image, converts X itself) ------
__global__ __launch_bounds__(640) void gemm_argmax_mid(
    const float* __restrict__ hid, const float* __restrict__ noise,
    const float* __restrict__ emb, const float* __restrict__ bias,
    const _Float16* __restrict__ wi,
    float* __restrict__ out, int* __restrict__ cnt)
{
    __shared__ __align__(16) _Float16 Xh[BM][KSTEP];
    __shared__ __align__(16) _Float16 Xl[BM][KSTEP];
    __shared__ int sel_n[BM][2];
    float* red_val = (float*)&Xh[0][0];
    int*   red_idx = (int*)&Xl[0][0];

    const int tid = threadIdx.x;
    const int w = tid >> 6;
    const int l = tid & 63;
    const int q = l & 15, g = l >> 4;
    const int sig = (q >> 1) & 3;
    const int sl = (g ^ sig) * 8;
    const int brow = blockIdx.x * BM;

    f32x4 acc[4][4];
    #pragma unroll
    for (int mt = 0; mt < 4; ++mt)
        #pragma unroll
        for (int nt = 0; nt < 4; ++nt) acc[mt][nt] = (f32x4){0.f, 0.f, 0.f, 0.f};

    const half8* wv = (const half8*)wi;

    for (int kt = 0; kt < NKT; ++kt) {
        __syncthreads();
        if (tid < 256) {
            int r = tid & 63, c = tid >> 6;
            const float* src = hid + (size_t)(brow + r) * H + kt * KSTEP + c * 8;
            float4 v0 = *(const float4*)src;
            float4 v1 = *(const float4*)(src + 4);
            float vv[8] = {v0.x, v0.y, v0.z, v0.w, v1.x, v1.y, v1.z, v1.w};
            half8 hv, lv;
            #pragma unroll
            for (int i = 0; i < 8; ++i) {
                float xs = vv[i] * 64.0f;
                _Float16 h = (_Float16)xs;
                hv[i] = h;
                lv[i] = (_Float16)(xs - (float)h);
            }
            int slot = c ^ ((r >> 1) & 3);
            *(half8*)&Xh[r][slot * 8] = hv;
            *(half8*)&Xl[r][slot * 8] = lv;
        }
        __syncthreads();
        half8 Ah[4], Al[4];
        #pragma unroll
        for (int mt = 0; mt < 4; ++mt) {
            int row = mt * 16 + q;
            Ah[mt] = *(const half8*)&Xh[row][sl];
            Al[mt] = *(const half8*)&Xl[row][sl];
        }
        const int gbase = (kt * 4 + g) * 640 + w * 64 + q;
        #pragma unroll
        for (int nt = 0; nt < 4; ++nt) {
            half8 Bh = wv[2 * (gbase + nt * 16)];
            half8 Bl = wv[2 * (gbase + nt * 16) + 1];
            #pragma unroll
            for (int mt = 0; mt < 4; ++mt) {
                acc[mt][nt] = __builtin_amdgcn_mfma_f32_16x16x32_f16(Ah[mt], Bh, acc[mt][nt], 0, 0, 0);
                acc[mt][nt] = __builtin_amdgcn_mfma_f32_16x16x32_f16(Ah[mt], Bl, acc[mt][nt], 0, 0, 0);
                acc[mt][nt] = __builtin_amdgcn_mfma_f32_16x16x32_f16(Al[mt], Bh, acc[mt][nt], 0, 0, 0);
            }
        }
    }
    __syncthreads();

    const float C1 = 1.52587890625e-05f;
    float bcol[4];
    #pragma unroll
    for (int nt = 0; nt < 4; ++nt) bcol[nt] = bias[w * 64 + nt * 16 + q];
    #pragma unroll
    for (int mt = 0; mt < 4; ++mt) {
        #pragma unroll
        for (int reg = 0; reg < 4; ++reg) {
            int r = mt * 16 + 4 * g + reg;
            float bv = -INFINITY;
            int bn = 0;
            #pragma unroll
            for (int nt = 0; nt < 4; ++nt) {
                int col = w * 64 + nt * 16 + q;
                float u = noise[(size_t)(brow + r) * GV + col];
                float gum = -logf(-logf(u + 1e-10f) + 1e-10f);
                float z = acc[mt][nt][reg] * C1 + bcol[nt] + gum;
                if (z > bv) { bv = z; bn = col; }
            }
            #pragma unroll
            for (int m = 1; m < 16; m <<= 1) {
                float ov = __shfl_xor(bv, m, 64);
                int on = __shfl_xor(bn, m, 64);
                if (ov > bv || (ov == bv && on < bn)) { bv = ov; bn = on; }
            }
            if (q == 0) { red_val[r * 10 + w] = bv; red_idx[r * 10 + w] = bn; }
        }
    }
    __syncthreads();
    if (tid < 128) {
        int r = tid >> 1, grp = tid & 1;
        float bv = -INFINITY;
        int bn = 0;
        #pragma unroll
        for (int ww = 0; ww < 5; ++ww) {
            int wiq = grp * 5 + ww;
            float v = red_val[r * 10 + wiq];
            int n = red_idx[r * 10 + wiq];
            if (v > bv) { bv = v; bn = n; }
        }
        atomicAdd(&cnt[bn], 1);
        sel_n[r][grp] = bn;
    }
    __syncthreads();
    if (tid < 512) {
        int rg = tid >> 2, sub = tid & 3;
        int r = rg >> 1, grp = rg & 1;
        int n = sel_n[r][grp];
        const float4* src = (const float4*)(emb + (size_t)n * E_DIM);
        float4* dst = (float4*)(out + (size_t)(brow + r) * 512 + grp * 256);
        #pragma unroll
        for (int j = 0; j < 16; ++j) dst[sub + j * 4] = src[sub + j * 4];
    }
}

// ---------------- last-resort fp32 fallback (round-1) ----------------
__global__ __launch_bounds__(512) void fused_gemm_argmax(
    const float* __restrict__ hid, const float* __restrict__ noise,
    const float* __restrict__ emb, const float* __restrict__ W,
    const float* __restrict__ bias, float* __restrict__ out, int* __restrict__ cnt)
{
    __shared__ float A_lds[16][64];
    __shared__ float B_lds[16][GV + 4];
    const int tid = threadIdx.x;
    const int tx = tid & 63, ty = tid >> 6;
    const int brow = blockIdx.x * 64;
    const int nbase = tx * 10;
    float acc[8][10];
    #pragma unroll
    for (int i = 0; i < 8; ++i)
        #pragma unroll
        for (int j = 0; j < 10; ++j) acc[i][j] = 0.f;
    for (int t = 0; t < H; t += 16) {
        if (t) __syncthreads();
        if (tid < 256) {
            int m = tid & 63, kq = tid >> 6;
            float4 v = *(const float4*)(hid + (size_t)(brow + m) * H + t + kq * 4);
            A_lds[kq * 4 + 0][m] = v.x; A_lds[kq * 4 + 1][m] = v.y;
            A_lds[kq * 4 + 2][m] = v.z; A_lds[kq * 4 + 3][m] = v.w;
        }
        #pragma unroll
        for (int s = 0; s < 5; ++s) {
            int c = tid + s * 512;
            int n = c % 640, kq = c / 640;
            float4 v = *(const float4*)(W + (size_t)n * H + t + kq * 4);
            B_lds[kq * 4 + 0][n] = v.x; B_lds[kq * 4 + 1][n] = v.y;
            B_lds[kq * 4 + 2][n] = v.z; B_lds[kq * 4 + 3][n] = v.w;
        }
        __syncthreads();
        #pragma unroll 4
        for (int kk = 0; kk < 16; ++kk) {
            float a[8], bb[10];
            #pragma unroll
            for (int i = 0; i < 8; ++i) a[i] = A_lds[kk][ty * 8 + i];
            #pragma unroll
            for (int j = 0; j < 10; ++j) bb[j] = B_lds[kk][nbase + j];
            #pragma unroll
            for (int i = 0; i < 8; ++i)
                #pragma unroll
                for (int j = 0; j < 10; ++j) acc[i][j] = fmaf(a[i], bb[j], acc[i][j]);
        }
    }
    float bs[10];
    #pragma unroll
    for (int j = 0; j < 10; ++j) bs[j] = bias[nbase + j];
    const int gg = tx >> 5, ll = tx & 31;
    #pragma unroll
    for (int i = 0; i < 8; ++i) {
        const int b = brow + ty * 8 + i;
        float best = -INFINITY; int bestn = nbase;
        #pragma unroll
        for (int j = 0; j < 10; ++j) {
            float u = noise[(size_t)b * GV + nbase + j];
            float gmb = -logf(-logf(u + 1e-10f) + 1e-10f);
            float z = acc[i][j] + bs[j] + gmb;
            if (z > best) { best = z; bestn = nbase + j; }
        }
        #pragma unroll
        for (int msk = 1; msk <= 16; msk <<= 1) {
            float oz = __shfl_xor(best, msk, 64);
            int on = __shfl_xor(bestn, msk, 64);
            if (oz > best || (oz == best && on < bestn)) { best = oz; bestn = on; }
        }
        if (ll == 0) atomicAdd(&cnt[bestn], 1);
        const float4* src = (const float4*)(emb + (size_t)bestn * E_DIM);
        float4* dst = (float4*)(out + (size_t)b * 512 + gg * 256);
        dst[ll] = src[ll];
        dst[ll + 32] = src[ll + 32];
    }
}

extern "C" void kernel_launch(void* const* d_in, const int* in_sizes, int n_in,
                              void* d_out, int out_size, void* d_ws, size_t ws_size,
                              hipStream_t stream)
{
    const float* hid   = (const float*)d_in[0];
    const float* noise = (const float*)d_in[1];
    const float* emb   = (const float*)d_in[2];
    const float* W     = (const float*)d_in[3];
    const float* bias  = (const float*)d_in[4];
    float* out = (float*)d_out;
    int* cnt = (int*)d_ws;
    const int B = in_sizes[0] / H;

    hipMemsetAsync(cnt, 0, GV * sizeof(int), stream);
    if (ws_size >= WS_NEED_FULL(B)) {
        _Float16* wi = (_Float16*)((char*)d_ws + WS_WI);
        _Float16* xi = (_Float16*)((char*)d_ws + WS_XI);
        float* cv = (float*)((char*)d_ws + WS_CVAL(B));
        int* ci = (int*)((char*)d_ws + WS_CIDX(B));
        prep_w<<<160, 256, 0, stream>>>(W, wi);
        prep_x<<<B / 4, 256, 0, stream>>>(hid, xi);
        gemm32i<<<(B / BM) * 5, 256, 0, stream>>>(noise, bias, wi, xi, cv, ci);
        reduce_gather<<<(B * 2) / 4, 256, 0, stream>>>(cv, ci, emb, out, cnt);
    } else if (ws_size >= (size_t)WS_NEED_MID) {
        _Float16* wi = (_Float16*)((char*)d_ws + WS_WI);
        prep_w<<<160, 256, 0, stream>>>(W, wi);
        gemm_argmax_mid<<<B / BM, 640, 0, stream>>>(hid, noise, emb, bias, wi, out, cnt);
    } else {
        fused_gemm_argmax<<<B / BM, 512, 0, stream>>>(hid, noise, emb, W, bias, out, cnt);
    }
    ppl_kernel<<<1, 64, 0, stream>>>(cnt, out + (size_t)B * 512);
}